// Round 5
// baseline (503.986 us; speedup 1.0000x reference)
//
#include <hip/hip_runtime.h>

// EdgeGATConv on MI355X — R5: atomic-free CSR fill (rank captured in hist) +
// non-temporal streaming to stop L2 thrash from the 102MB ea stream and the
// scattered record stores.
// Pipeline:
//   k_node_proj : src_proj_bf16 = bf16(x@W_src+b); alpha_sn/alpha_dn fp32 dots
//   k_prep      : V[k,h] = reduce(W_edge, att_edge), + reduced bias
//   k_hist      : rank[e] = cnt[dst]++   (atomic returns old = stable rank)
//   k_scan_*    : parallel exclusive scan cnt -> row_start
//   k_fill      : w = exp(leaky(...)); slot = row_start[dst]+rank[e];
//                 nt-store rec[slot] = {src, bf16 w x4}  (no atomics)
//   k_gather    : wave per node, unroll-4, nt rec loads; out = acc/(denom+eps)

#define N_NODES 100000
#define N_EDGES 1600000
#define SCAN_B 1024
#define SCAN_NBLK ((N_NODES + SCAN_B - 1) / SCAN_B)   // 98

typedef int   v4i __attribute__((ext_vector_type(4)));
typedef float v4f __attribute__((ext_vector_type(4)));

// float -> bf16 bits, round-to-nearest-even (no NaN inputs here)
static __device__ __forceinline__ unsigned int f2bf(float f) {
    unsigned int u = __float_as_uint(f);
    return (u + 0x7fffu + ((u >> 16) & 1u)) >> 16;
}
static __device__ __forceinline__ float bf2f(unsigned int bits16) {
    return __uint_as_float(bits16 << 16);
}

__global__ __launch_bounds__(256) void k_node_proj(
    const float* __restrict__ x, const float* __restrict__ Wsrc,
    const float* __restrict__ bsrc, const float* __restrict__ Wdst,
    const float* __restrict__ bdst, const float* __restrict__ att_src,
    const float* __restrict__ att_dst, unsigned short* __restrict__ spbf,
    float* __restrict__ alpha_sn, float* __restrict__ alpha_dn)
{
    __shared__ float xs[32 * 128];              // 16 KB: 32 node rows
    const int tid = threadIdx.x;
    const int nbase = blockIdx.x * 32;

    const v4f* xsrc = (const v4f*)(x + (size_t)nbase * 128);
    v4f* xd = (v4f*)xs;
#pragma unroll
    for (int i = 0; i < 4; ++i)
        xd[tid + i * 256] = __builtin_nontemporal_load(xsrc + tid + i * 256);
    __syncthreads();

    const int col = tid & 63;
    const int g = tid >> 6;                     // wave id 0..3, nodes g*8..g*8+7

    float accS[8], accD[8];
#pragma unroll
    for (int i = 0; i < 8; ++i) { accS[i] = 0.f; accD[i] = 0.f; }

    for (int k4 = 0; k4 < 128; k4 += 4) {
        v4f xv[8];
#pragma unroll
        for (int i = 0; i < 8; ++i)
            xv[i] = *(const v4f*)&xs[(g * 8 + i) * 128 + k4];
#pragma unroll
        for (int kk = 0; kk < 4; ++kk) {
            float wsv = Wsrc[(k4 + kk) * 64 + col];
            float wdv = Wdst[(k4 + kk) * 64 + col];
#pragma unroll
            for (int i = 0; i < 8; ++i) {
                float xvk = xv[i][kk];
                accS[i] = fmaf(xvk, wsv, accS[i]);
                accD[i] = fmaf(xvk, wdv, accD[i]);
            }
        }
    }

    const float bs = bsrc[col], bd = bdst[col];
    const float as_ = att_src[col], ad_ = att_dst[col];
    const int h = col >> 4;
#pragma unroll
    for (int i = 0; i < 8; ++i) {
        const int n = nbase + g * 8 + i;
        float vS = accS[i] + bs;
        float vD = accD[i] + bd;
        spbf[(size_t)n * 64 + col] = (unsigned short)f2bf(vS);
        float t1 = vS * as_;
        float t2 = vD * ad_;
#pragma unroll
        for (int off = 8; off >= 1; off >>= 1) {
            t1 += __shfl_xor(t1, off, 16);
            t2 += __shfl_xor(t2, off, 16);
        }
        if ((col & 15) == 0) {
            alpha_sn[n * 4 + h] = t1;
            alpha_dn[n * 4 + h] = t2;
        }
    }
}

__global__ void k_prep(const float* __restrict__ We, const float* __restrict__ be,
                       const float* __restrict__ att_e, float* __restrict__ V)
{
    const int t = threadIdx.x;            // 64 threads
    const int k = t >> 2, h = t & 3;
    float acc = 0.f;
    for (int c = 0; c < 16; ++c)
        acc += We[k * 64 + h * 16 + c] * att_e[h * 16 + c];
    V[k * 4 + h] = acc;
    if (t < 4) {
        float b = 0.f;
        for (int c = 0; c < 16; ++c)
            b += be[t * 16 + c] * att_e[t * 16 + c];
        V[64 + t] = b;
    }
}

// rank[e] = order of edge e within its dst segment (atomic old value)
__global__ __launch_bounds__(256) void k_hist(const int* __restrict__ ei,
                                               int* __restrict__ cnt,
                                               int* __restrict__ rank)
{
    const int e = blockIdx.x * 256 + threadIdx.x;
    if (e >= N_EDGES) return;
    const int dst = __builtin_nontemporal_load(&ei[N_EDGES + e]);
    const int r = atomicAdd(&cnt[dst], 1);
    __builtin_nontemporal_store(r, &rank[e]);
}

__global__ __launch_bounds__(256) void k_scan_part(const int* __restrict__ cnt,
                                                    int* __restrict__ partial)
{
    __shared__ int red[4];
    const int t = threadIdx.x;
    const int base = blockIdx.x * SCAN_B + t * 4;
    int s = 0;
#pragma unroll
    for (int i = 0; i < 4; ++i) {
        const int idx = base + i;
        if (idx < N_NODES) s += cnt[idx];
    }
#pragma unroll
    for (int off = 32; off >= 1; off >>= 1)
        s += __shfl_xor(s, off, 64);
    if ((t & 63) == 0) red[t >> 6] = s;
    __syncthreads();
    if (t == 0)
        partial[blockIdx.x] = red[0] + red[1] + red[2] + red[3];
}

__global__ __launch_bounds__(128) void k_scan_top(int* __restrict__ partial)
{
    __shared__ int sums[128];
    const int t = threadIdx.x;
    sums[t] = (t < SCAN_NBLK) ? partial[t] : 0;
    __syncthreads();
#pragma unroll
    for (int off = 1; off < 128; off <<= 1) {
        int v = (t >= off) ? sums[t - off] : 0;
        __syncthreads();
        sums[t] += v;
        __syncthreads();
    }
    if (t < SCAN_NBLK) partial[t] = (t == 0) ? 0 : sums[t - 1];
}

__global__ __launch_bounds__(256) void k_scan_down(
    const int* __restrict__ cnt, const int* __restrict__ partial,
    int* __restrict__ row_start)
{
    __shared__ int tsum[256];
    const int t = threadIdx.x;
    const int base = blockIdx.x * SCAN_B + t * 4;
    int c[4];
#pragma unroll
    for (int i = 0; i < 4; ++i) {
        const int idx = base + i;
        c[i] = (idx < N_NODES) ? cnt[idx] : 0;
    }
    const int tot = c[0] + c[1] + c[2] + c[3];
    tsum[t] = tot;
    __syncthreads();
#pragma unroll
    for (int off = 1; off < 256; off <<= 1) {
        int v = (t >= off) ? tsum[t - off] : 0;
        __syncthreads();
        tsum[t] += v;
        __syncthreads();
    }
    int run = partial[blockIdx.x] + ((t == 0) ? 0 : tsum[t - 1]);
#pragma unroll
    for (int i = 0; i < 4; ++i) {
        const int idx = base + i;
        if (idx < N_NODES) row_start[idx] = run;
        run += c[i];
    }
    if (blockIdx.x == 0 && t == 0)
        row_start[N_NODES] = N_EDGES;
}

__global__ __launch_bounds__(256) void k_fill(
    const int* __restrict__ ei, const float* __restrict__ ea,
    const float* __restrict__ V, const float* __restrict__ alpha_sn,
    const float* __restrict__ alpha_dn, const int* __restrict__ row_start,
    const int* __restrict__ rank, v4i* __restrict__ rec)
{
    __shared__ float Vs[68];
    if (threadIdx.x < 68) Vs[threadIdx.x] = V[threadIdx.x];
    __syncthreads();

    const int e = blockIdx.x * 256 + threadIdx.x;
    if (e >= N_EDGES) return;
    const int src = __builtin_nontemporal_load(&ei[e]);
    const int dst = __builtin_nontemporal_load(&ei[N_EDGES + e]);

    const v4f* ea4 = (const v4f*)(ea + (size_t)e * 16);
    const v4f c0 = __builtin_nontemporal_load(ea4 + 0);
    const v4f c1 = __builtin_nontemporal_load(ea4 + 1);
    const v4f c2 = __builtin_nontemporal_load(ea4 + 2);
    const v4f c3 = __builtin_nontemporal_load(ea4 + 3);
    float ek[16];
#pragma unroll
    for (int i = 0; i < 4; ++i) {
        ek[i] = c0[i]; ek[4 + i] = c1[i]; ek[8 + i] = c2[i]; ek[12 + i] = c3[i];
    }
    float a[4] = {Vs[64], Vs[65], Vs[66], Vs[67]};
#pragma unroll
    for (int k = 0; k < 16; ++k) {
#pragma unroll
        for (int h = 0; h < 4; ++h)
            a[h] = fmaf(ek[k], Vs[k * 4 + h], a[h]);
    }

    const float4 asn = *(const float4*)(alpha_sn + (size_t)src * 4);
    const float4 adn = *(const float4*)(alpha_dn + (size_t)dst * 4);
    float a0 = a[0] + asn.x + adn.x;
    float a1 = a[1] + asn.y + adn.y;
    float a2 = a[2] + asn.z + adn.z;
    float a3 = a[3] + asn.w + adn.w;
    a0 = (a0 >= 0.f) ? a0 : 0.2f * a0;
    a1 = (a1 >= 0.f) ? a1 : 0.2f * a1;
    a2 = (a2 >= 0.f) ? a2 : 0.2f * a2;
    a3 = (a3 >= 0.f) ? a3 : 0.2f * a3;

    const unsigned int w01 = f2bf(__expf(a0)) | (f2bf(__expf(a1)) << 16);
    const unsigned int w23 = f2bf(__expf(a2)) | (f2bf(__expf(a3)) << 16);

    const int slot = row_start[dst] + __builtin_nontemporal_load(&rank[e]);
    v4i r;
    r[0] = src; r[1] = (int)w01; r[2] = (int)w23; r[3] = 0;
    __builtin_nontemporal_store(r, rec + slot);
}

// one wave per node; unroll-4 over incoming edges for memory-level parallelism
__global__ __launch_bounds__(256) void k_gather(
    const int* __restrict__ row_start, const v4i* __restrict__ rec,
    const unsigned short* __restrict__ spbf, float* __restrict__ out)
{
    const int lane = threadIdx.x & 63;
    const int node = (blockIdx.x * 256 + threadIdx.x) >> 6;
    const int h = lane >> 4;
    const int base = row_start[node];
    const int end = row_start[node + 1];

    float acc = 0.f, denom = 0.f;
    int j = base;
    for (; j + 4 <= end; j += 4) {
        const v4i r0 = __builtin_nontemporal_load(rec + j);
        const v4i r1 = __builtin_nontemporal_load(rec + j + 1);
        const v4i r2 = __builtin_nontemporal_load(rec + j + 2);
        const v4i r3 = __builtin_nontemporal_load(rec + j + 3);
        const float v0 = bf2f(spbf[((size_t)r0[0] << 6) + lane]);
        const float v1 = bf2f(spbf[((size_t)r1[0] << 6) + lane]);
        const float v2 = bf2f(spbf[((size_t)r2[0] << 6) + lane]);
        const float v3 = bf2f(spbf[((size_t)r3[0] << 6) + lane]);
#define WEXT(r) bf2f(((h & 1) ? ((unsigned int)((h < 2) ? r[1] : r[2]) >> 16) \
                              : ((unsigned int)((h < 2) ? r[1] : r[2]) & 0xffffu)))
        const float w0 = WEXT(r0), w1 = WEXT(r1), w2 = WEXT(r2), w3 = WEXT(r3);
        denom += (w0 + w1) + (w2 + w3);
        acc = fmaf(w0, v0, acc);
        acc = fmaf(w1, v1, acc);
        acc = fmaf(w2, v2, acc);
        acc = fmaf(w3, v3, acc);
    }
    for (; j < end; ++j) {
        const v4i r0 = __builtin_nontemporal_load(rec + j);
        const float v0 = bf2f(spbf[((size_t)r0[0] << 6) + lane]);
        const float w0 = WEXT(r0);
        denom += w0;
        acc = fmaf(w0, v0, acc);
    }
#undef WEXT
    __builtin_nontemporal_store(acc / (denom + 1e-16f),
                                &out[(size_t)node * 64 + lane]);
}

extern "C" void kernel_launch(void* const* d_in, const int* in_sizes, int n_in,
                              void* d_out, int out_size, void* d_ws, size_t ws_size,
                              hipStream_t stream) {
    const float* x     = (const float*)d_in[0];
    const int*   ei    = (const int*)d_in[1];
    const float* ea    = (const float*)d_in[2];
    const float* Wsrc  = (const float*)d_in[3];
    const float* bsrc  = (const float*)d_in[4];
    const float* Wdst  = (const float*)d_in[5];
    const float* bdst  = (const float*)d_in[6];
    const float* We    = (const float*)d_in[7];
    const float* be    = (const float*)d_in[8];
    const float* att_s = (const float*)d_in[9];
    const float* att_d = (const float*)d_in[10];
    const float* att_e = (const float*)d_in[11];
    float* out = (float*)d_out;

    // workspace layout — rec first for 16B alignment; ~48 MB total
    v4i*   rec       = (v4i*)d_ws;                             // E*16B = 25.6 MB
    unsigned short* spbf = (unsigned short*)(rec + N_EDGES);   // N*64*2B = 12.8 MB
    float* alpha_sn  = (float*)(spbf + (size_t)N_NODES * 64);  // N*4 (16B-aligned)
    float* alpha_dn  = alpha_sn + (size_t)N_NODES * 4;         // N*4
    int*   rank      = (int*)(alpha_dn + (size_t)N_NODES * 4); // E
    int*   cnt       = rank + N_EDGES;                         // N
    int*   row_start = cnt + N_NODES;                          // N+1 (pad 4)
    int*   partial   = row_start + N_NODES + 4;                // 128
    float* V         = (float*)(partial + 128);                // 68

    hipMemsetAsync(cnt, 0, (size_t)N_NODES * sizeof(int), stream);

    k_node_proj<<<N_NODES / 32, 256, 0, stream>>>(x, Wsrc, bsrc, Wdst, bdst,
                                                  att_s, att_d, spbf,
                                                  alpha_sn, alpha_dn);
    k_prep<<<1, 64, 0, stream>>>(We, be, att_e, V);
    k_hist<<<N_EDGES / 256, 256, 0, stream>>>(ei, cnt, rank);
    k_scan_part<<<SCAN_NBLK, 256, 0, stream>>>(cnt, partial);
    k_scan_top<<<1, 128, 0, stream>>>(partial);
    k_scan_down<<<SCAN_NBLK, 256, 0, stream>>>(cnt, partial, row_start);
    k_fill<<<N_EDGES / 256, 256, 0, stream>>>(ei, ea, V, alpha_sn, alpha_dn,
                                              row_start, rank, rec);
    k_gather<<<(N_NODES + 3) / 4, 256, 0, stream>>>(row_start, rec, spbf, out);
}